// Round 12
// baseline (255.152 us; speedup 1.0000x reference)
//
#include <hip/hip_runtime.h>
#include <hip/hip_cooperative_groups.h>
#include <stdint.h>

namespace cg = cooperative_groups;

#define GXC 512
#define GYC 512
#define GXY (GXC * GYC)     // 262144 voxels per batch
#define NB  512             // place blocks
#define SC  8192            // points per block = one flush
#define PT  1024            // place threads per block
#define SPT (SC / PT)       // staged points per thread = 8
#define LBINS 512           // local bins = GXC
#define XG  4               // bins per rowreduce block (fallback path)
#define XG2 16              // bins per fused block (cooperative path)
#define BPB (GXY / 256)     // fallback fill blocks per batch

typedef float v4f __attribute__((ext_vector_type(4)));
typedef float v2f __attribute__((ext_vector_type(2)));
typedef int   v2i __attribute__((ext_vector_type(2)));

// ---- monotone float <-> sortable-uint mapping ----
__device__ __forceinline__ unsigned f2s(float f) {
    unsigned u = __float_as_uint(f);
    return (u & 0x80000000u) ? ~u : (u | 0x80000000u);
}
__device__ __forceinline__ float s2f(unsigned u) {
    return (u & 0x80000000u) ? __uint_as_float(u ^ 0x80000000u)
                             : __uint_as_float(~u);
}
// key = [ f2s(z) : 32 | f2s(r) top 23 bits | y : 9 ] (R9-verified).
__device__ __forceinline__ unsigned long long packkey_y(float z, float r,
                                                        unsigned y) {
    return ((unsigned long long)f2s(z) << 32)
         | (unsigned long long)((f2s(r) & ~511u) | y);
}
__device__ __forceinline__ unsigned long long packkey(float z, float r) {
    return ((unsigned long long)f2s(z) << 32) | (unsigned long long)f2s(r);
}

// XCD swizzle (locality heuristic ONLY).
__device__ __forceinline__ int swizzle(int g, int swz) {
    return swz ? ((g & 7) * (NB / 8) + (g >> 3)) : g;
}

// ================= K1: placement (unchanged structure; zr now an 8B load
// instead of the full 16B float4 -> -32MB input traffic) =================
__global__ __launch_bounds__(1024)
void place_kernel(const v2f* __restrict__ zr, const v2i* __restrict__ xy,
                  unsigned long long* __restrict__ keyA,
                  unsigned* __restrict__ meta, int swz) {
    __shared__ unsigned long long skey[SC];       // 64 KB
    __shared__ unsigned lcnt[LBINS], loff[LBINS]; // 4 KB
    __shared__ unsigned wsum[8];
    int t = threadIdx.x;
    int blk = swizzle(blockIdx.x, swz);
    int start = blk * SC;
    if (t < LBINS) lcnt[t] = 0;
    __syncthreads();

    unsigned long long k[SPT]; unsigned lb[SPT], rk[SPT];
    #pragma unroll
    for (int kk = 0; kk < SPT; ++kk) {
        int p = start + t + kk * PT;
        v2i q = __builtin_nontemporal_load(xy + p);
        v2f f = __builtin_nontemporal_load(zr + 2 * p + 1);  // (z, r) at +8B
        k[kk]  = packkey_y(f.x, f.y, (unsigned)q.y);
        lb[kk] = (unsigned)q.x;
        rk[kk] = atomicAdd(&lcnt[q.x], 1u);
    }
    __syncthreads();

    unsigned c = 0, inc = 0;
    if (t < LBINS) {
        c = lcnt[t];
        inc = c;
        int lane = t & 63;
        #pragma unroll
        for (int off = 1; off < 64; off <<= 1) {
            unsigned o = __shfl_up(inc, off);
            if (lane >= off) inc += o;
        }
        if (lane == 63) wsum[t >> 6] = inc;
    }
    __syncthreads();
    if (t < 8) {
        unsigned v = wsum[t], i2 = v;
        #pragma unroll
        for (int off = 1; off < 8; off <<= 1) {
            unsigned o = __shfl_up(i2, off, 8);
            if (t >= off) i2 += o;
        }
        wsum[t] = i2 - v;
    }
    __syncthreads();
    if (t < LBINS) loff[t] = inc - c + wsum[t >> 6];
    __syncthreads();

    #pragma unroll
    for (int kk = 0; kk < SPT; ++kk)
        skey[loff[lb[kk]] + rk[kk]] = k[kk];
    __syncthreads();

    unsigned long long* dst = keyA + (size_t)blk * SC;
    #pragma unroll
    for (int kk = 0; kk < SPT; ++kk) {
        int s = t + kk * PT;
        dst[s] = skey[s];
    }
    if (t < LBINS)
        meta[(size_t)blk * LBINS + t] = (loff[t] << 16) | lcnt[t];
}

// ================= K2 (cooperative): rowreduce + mn/mx + norm fused =========
// 512 blocks x 512 threads, XG2=16 bins/block, LDS ~75KB -> 2 blocks/CU,
// grid exactly co-resident. Phase A: slice gather (~2KB contiguous/segment)
// into LDS sk/byte-packed counts; partials via plain stores. grid.sync().
// Phase B: 96 blocks reduce partials -> mn|mx. grid.sync(). Phase C: each
// block normalizes ITS OWN LDS voxels and writes out once, nontemporal —
// kills the R11 write-unnormalized/read/rewrite 100MB round-trip.
__global__ __launch_bounds__(512)
void fused_kernel(const unsigned long long* __restrict__ keyA,
                  const unsigned* __restrict__ meta,
                  float* __restrict__ out,
                  float* __restrict__ partials,
                  float* __restrict__ mnmx,     // [0..3B)=mn, [3B..6B)=mx
                  int bpblk, int B) {
    __shared__ unsigned long long sk[XG2 * 512];         // 64 KB
    __shared__ unsigned scnt32[(XG2 * 512) / 4];         // 8 KB (u8-packed)
    __shared__ unsigned short bnd[32][XG2 + 1];          // slice boundaries
    __shared__ unsigned slo[32];
    __shared__ float red[8][6];
    cg::grid_group grid = cg::this_grid();
    int t = threadIdx.x;
    int g = blockIdx.x;
    int batch = g >> 5;                   // 32 x-groups per batch
    int x0 = (g & 31) * XG2;

    for (int i = t; i < XG2 * 512; i += 512) sk[i] = 0;
    for (int i = t; i < (XG2 * 512) / 4; i += 512) scnt32[i] = 0;

    // ---- phase A: gather + LDS reduce ----
    int seg = t >> 4, l16 = t & 15;       // 16 lanes per segment, 32 segments
    size_t sidx = (size_t)(batch * bpblk + seg);
    unsigned m = meta[sidx * LBINS + x0 + l16];
    unsigned pc = m & 0xFFFFu, ip = pc;
    #pragma unroll
    for (int off = 1; off < 16; off <<= 1) {
        unsigned o = __shfl_up(ip, off, 16);
        if (l16 >= off) ip += o;
    }
    bnd[seg][l16 + 1] = (unsigned short)ip;
    if (l16 == 0) { bnd[seg][0] = 0; slo[seg] = m >> 16; }
    __syncthreads();

    unsigned tot = bnd[seg][XG2];
    const unsigned long long* src = keyA + sidx * SC + slo[seg];
    unsigned b = 0;
    for (unsigned r = l16; r < tot; r += 16) {
        while (r >= bnd[seg][b + 1]) ++b;     // monotone, amortized O(1)
        unsigned long long k = src[r];
        unsigned idx = (b << 9) | ((unsigned)k & 511u);
        atomicMax(&sk[idx], k);
        atomicAdd(&scnt32[idx >> 2], 1u << ((idx & 3) * 8));
    }
    __syncthreads();

    float n0 = INFINITY, mx0 = -INFINITY, n1 = INFINITY, mx1 = -INFINITY,
          n2 = INFINITY, mx2 = -INFINITY;
    for (int i = t; i < XG2 * 512; i += 512) {
        unsigned cv = (scnt32[i >> 2] >> ((i & 3) * 8)) & 255u;
        float h0 = 0.0f, r = 0.0f;
        if (cv) {
            unsigned long long k = sk[i];
            h0 = s2f((unsigned)(k >> 32));
            r  = s2f((unsigned)k & ~511u);
        }
        float cf = (float)cv;
        n0 = fminf(n0, h0); mx0 = fmaxf(mx0, h0);
        n1 = fminf(n1, r);  mx1 = fmaxf(mx1, r);
        n2 = fminf(n2, cf); mx2 = fmaxf(mx2, cf);
    }
    #pragma unroll
    for (int off = 32; off; off >>= 1) {
        n0 = fminf(n0, __shfl_down(n0, off));  mx0 = fmaxf(mx0, __shfl_down(mx0, off));
        n1 = fminf(n1, __shfl_down(n1, off));  mx1 = fmaxf(mx1, __shfl_down(mx1, off));
        n2 = fminf(n2, __shfl_down(n2, off));  mx2 = fmaxf(mx2, __shfl_down(mx2, off));
    }
    int lane = t & 63, wave = t >> 6;
    if (lane == 0) {
        red[wave][0] = n0; red[wave][1] = mx0;
        red[wave][2] = n1; red[wave][3] = mx1;
        red[wave][4] = n2; red[wave][5] = mx2;
    }
    __syncthreads();
    if (t < 6) {
        float v = red[0][t];
        bool isMin = (t & 1) == 0;
        #pragma unroll
        for (int w = 1; w < 8; ++w)
            v = isMin ? fminf(v, red[w][t]) : fmaxf(v, red[w][t]);
        partials[(size_t)g * 6 + t] = v;
    }
    grid.sync();

    // ---- phase B: 96 blocks reduce 32 partials each -> mn|mx ----
    if (g < B * 6) {
        int bb = g / 6, j = g - bb * 6;
        bool isMin = (j & 1) == 0;
        if (t < 32) {
            float v = partials[(size_t)(bb * 32 + t) * 6 + j];
            #pragma unroll
            for (int off = 16; off; off >>= 1) {
                float o = __shfl_down(v, off, 32);
                v = isMin ? fminf(v, o) : fmaxf(v, o);
            }
            if (t == 0) {
                int slot = bb * 3 + (j >> 1);
                mnmx[(isMin ? 0 : 3 * B) + slot] = v;
            }
        }
    }
    grid.sync();

    // ---- phase C: normalize from LDS, single nontemporal out write ----
    float lo0 = mnmx[batch * 3 + 0], iv0 = 1.0f / (mnmx[3 * B + batch * 3 + 0] - lo0);
    float lo1 = mnmx[batch * 3 + 1], iv1 = 1.0f / (mnmx[3 * B + batch * 3 + 1] - lo1);
    float lo2 = mnmx[batch * 3 + 2], iv2 = 1.0f / (mnmx[3 * B + batch * 3 + 2] - lo2);
    size_t ob = ((size_t)batch * 3) << 18;
    size_t xoff = (size_t)x0 << 9;
    for (int i = t; i < XG2 * 512; i += 512) {
        unsigned cv = (scnt32[i >> 2] >> ((i & 3) * 8)) & 255u;
        float h0 = 0.0f, r = 0.0f;
        if (cv) {
            unsigned long long k = sk[i];
            h0 = s2f((unsigned)(k >> 32));
            r  = s2f((unsigned)k & ~511u);
        }
        float cf = (float)cv;
        __builtin_nontemporal_store((h0 - lo0) * iv0, out + ob + xoff + i);
        __builtin_nontemporal_store((r  - lo1) * iv1, out + ob + (size_t)GXY + xoff + i);
        __builtin_nontemporal_store((cf - lo2) * iv2, out + ob + (size_t)(2 * GXY) + xoff + i);
    }
}

// ============ fallback chain (R11-proven): rowreduce + reduce + norm ========
__global__ __launch_bounds__(512)
void rowreduce_kernel(const unsigned long long* __restrict__ keyA,
                      const unsigned* __restrict__ meta,
                      float* __restrict__ out,
                      float* __restrict__ partials,
                      int bpblk) {
    __shared__ unsigned long long sk[XG * 512];
    __shared__ unsigned scnt[XG * 512];
    __shared__ float red[8][6];
    int t = threadIdx.x;
    int g = blockIdx.x;
    int batch = g >> 7;
    int x0 = (g & 127) * XG;
    for (int i = t; i < XG * 512; i += 512) { sk[i] = 0; scnt[i] = 0; }
    __syncthreads();
    int seg = t >> 4, l16 = t & 15;
    size_t sidx = (size_t)(batch * bpblk + seg);
    uint4 m = *(const uint4*)(meta + sidx * LBINS + x0);
    unsigned lo0 = m.x >> 16;
    unsigned b1 = m.x & 0xFFFFu;
    unsigned b2 = b1 + (m.y & 0xFFFFu);
    unsigned b3 = b2 + (m.z & 0xFFFFu);
    unsigned tot = b3 + (m.w & 0xFFFFu);
    const unsigned long long* src = keyA + sidx * SC + lo0;
    for (unsigned r = l16; r < tot; r += 16) {
        unsigned long long k = src[r];
        int bin = (r >= b1) + (r >= b2) + (r >= b3);
        unsigned y = (unsigned)k & 511u;
        atomicMax(&sk[(bin << 9) + y], k);
        atomicAdd(&scnt[(bin << 9) + y], 1u);
    }
    __syncthreads();
    size_t ob = ((size_t)batch * 3) << 18;
    size_t xoff = (size_t)x0 << 9;
    float n0 = INFINITY, mx0 = -INFINITY, n1 = INFINITY, mx1 = -INFINITY,
          n2 = INFINITY, mx2 = -INFINITY;
    for (int i = t; i < XG * 512; i += 512) {
        unsigned cv = scnt[i];
        float h0 = 0.0f, r = 0.0f;
        if (cv) {
            unsigned long long k = sk[i];
            h0 = s2f((unsigned)(k >> 32));
            r  = s2f((unsigned)k & ~511u);
        }
        float cf = (float)cv;
        out[ob + xoff + i] = h0;
        out[ob + (size_t)GXY + xoff + i] = r;
        out[ob + (size_t)(2 * GXY) + xoff + i] = cf;
        n0 = fminf(n0, h0); mx0 = fmaxf(mx0, h0);
        n1 = fminf(n1, r);  mx1 = fmaxf(mx1, r);
        n2 = fminf(n2, cf); mx2 = fmaxf(mx2, cf);
    }
    #pragma unroll
    for (int off = 32; off; off >>= 1) {
        n0 = fminf(n0, __shfl_down(n0, off));  mx0 = fmaxf(mx0, __shfl_down(mx0, off));
        n1 = fminf(n1, __shfl_down(n1, off));  mx1 = fmaxf(mx1, __shfl_down(mx1, off));
        n2 = fminf(n2, __shfl_down(n2, off));  mx2 = fmaxf(mx2, __shfl_down(mx2, off));
    }
    int lane = t & 63, wave = t >> 6;
    if (lane == 0) {
        red[wave][0] = n0; red[wave][1] = mx0;
        red[wave][2] = n1; red[wave][3] = mx1;
        red[wave][4] = n2; red[wave][5] = mx2;
    }
    __syncthreads();
    if (t < 6) {
        float v = red[0][t];
        bool isMin = (t & 1) == 0;
        #pragma unroll
        for (int w = 1; w < 8; ++w)
            v = isMin ? fminf(v, red[w][t]) : fmaxf(v, red[w][t]);
        partials[(size_t)g * 6 + t] = v;
    }
}

__global__ void reduce_kernel(const float* __restrict__ partials,
                              float* __restrict__ mn,
                              float* __restrict__ mx,
                              int rows) {
    int b = blockIdx.x / 6;
    int j = blockIdx.x - b * 6;
    bool isMin = (j & 1) == 0;
    float v = isMin ? INFINITY : -INFINITY;
    for (int i = threadIdx.x; i < rows; i += blockDim.x) {
        float p = partials[((size_t)b * rows + i) * 6 + j];
        v = isMin ? fminf(v, p) : fmaxf(v, p);
    }
    #pragma unroll
    for (int off = 32; off; off >>= 1) {
        float o = __shfl_down(v, off);
        v = isMin ? fminf(v, o) : fmaxf(v, o);
    }
    __shared__ float red[4];
    int lane = threadIdx.x & 63, wave = threadIdx.x >> 6;
    if (lane == 0) red[wave] = v;
    __syncthreads();
    if (threadIdx.x == 0) {
        #pragma unroll
        for (int w = 1; w < 4 && w < (int)(blockDim.x >> 6); ++w)
            v = isMin ? fminf(v, red[w]) : fmaxf(v, red[w]);
        int slot = b * 3 + (j >> 1);
        if (isMin) mn[slot] = v; else mx[slot] = v;
    }
}

__global__ void norm_kernel(v4f* __restrict__ out,
                            const float* __restrict__ mn,
                            const float* __restrict__ mx,
                            int total4) {
    int i = blockIdx.x * blockDim.x + threadIdx.x;
    if (i >= total4) return;
    int slot = i >> 16;
    float lo = mn[slot];
    float inv = 1.0f / (mx[slot] - lo);
    v4f v = __builtin_nontemporal_load(out + i);
    v.x = (v.x - lo) * inv;
    v.y = (v.y - lo) * inv;
    v.z = (v.z - lo) * inv;
    v.w = (v.w - lo) * inv;
    __builtin_nontemporal_store(v, out + i);
}

// ================= fallback path (R4 structure) =================
__global__ void scatter_fb(const v4f* __restrict__ fea, const v2i* __restrict__ xy,
                           unsigned long long* __restrict__ keys,
                           unsigned* __restrict__ cnt32, int N, int P) {
    int p = blockIdx.x * blockDim.x + threadIdx.x;
    if (p >= P) return;
    v2i q = __builtin_nontemporal_load(xy + p);
    v4f f = __builtin_nontemporal_load(fea + p);
    int vid = ((p / N) * GXC + q.x) * GYC + q.y;
    atomicMax(&keys[vid], packkey(f.z, f.w));
    atomicAdd(&cnt32[vid >> 2], 1u << ((vid & 3) * 8));
}

__global__ void fill_fb(const unsigned long long* __restrict__ keys,
                        const unsigned char* __restrict__ cntB,
                        float* __restrict__ out, float* __restrict__ partials) {
    int g = blockIdx.x;
    int batch = g / BPB, blkInB = g - batch * BPB;
    int rem = blkInB * 256 + threadIdx.x;
    int s = batch * GXY + rem;
    unsigned c = cntB[s];
    float h0 = 0.0f, r = 0.0f;
    if (c) {
        unsigned long long k = keys[s];
        h0 = s2f((unsigned)(k >> 32));
        r  = s2f((unsigned)(k & 0xFFFFFFFFull));
    }
    float cf = (float)c;
    size_t base = (size_t)batch * 3 * GXY + rem;
    out[base] = h0; out[base + GXY] = r; out[base + 2 * GXY] = cf;
    float n0 = h0, x0 = h0, n1 = r, x1 = r, n2 = cf, x2 = cf;
    #pragma unroll
    for (int off = 32; off; off >>= 1) {
        n0 = fminf(n0, __shfl_down(n0, off)); x0 = fmaxf(x0, __shfl_down(x0, off));
        n1 = fminf(n1, __shfl_down(n1, off)); x1 = fmaxf(x1, __shfl_down(x1, off));
        n2 = fminf(n2, __shfl_down(n2, off)); x2 = fmaxf(x2, __shfl_down(x2, off));
    }
    __shared__ float red[4][6];
    int lane = threadIdx.x & 63, wave = threadIdx.x >> 6;
    if (lane == 0) {
        red[wave][0] = n0; red[wave][1] = x0; red[wave][2] = n1;
        red[wave][3] = x1; red[wave][4] = n2; red[wave][5] = x2;
    }
    __syncthreads();
    if (threadIdx.x < 6) {
        int j = threadIdx.x;
        float v = red[0][j];
        bool isMin = (j & 1) == 0;
        #pragma unroll
        for (int w = 1; w < 4; ++w)
            v = isMin ? fminf(v, red[w][j]) : fmaxf(v, red[w][j]);
        partials[(size_t)(batch * BPB + blkInB) * 6 + j] = v;
    }
}

extern "C" void kernel_launch(void* const* d_in, const int* in_sizes, int n_in,
                              void* d_out, int out_size, void* d_ws, size_t ws_size,
                              hipStream_t stream) {
    const v4f* fea = (const v4f*)d_in[0];   // [B, N, 4] f32
    const v2i* xy  = (const v2i*)d_in[1];   // [B, N, 2] i32

    int P = in_sizes[0] / 4;
    int B = out_size / (3 * GXY);
    int N = (B > 0) ? P / B : 0;
    int S = B * GXY;
    int NBIN = B * GXC;
    int bpblk = (B > 0) ? NB / B : 0;

    char* ws = (char*)d_ws;
    unsigned long long* keyA = (unsigned long long*)ws;
    size_t o = (size_t)P * 8;
    unsigned* meta = (unsigned*)(ws + o);   o += (size_t)NB * LBINS * 4;
    float* partials = (float*)(ws + o);     o += (size_t)(NBIN / XG) * 6 * 4;
    float* mn = (float*)(ws + o);           o += (size_t)B * 3 * 4;
    float* mx = (float*)(ws + o);           o += (size_t)B * 3 * 4;   // mn,mx adjacent
    size_t need = o;

    int swz = (B % 8 == 0) ? 1 : 0;

    bool ok = B > 0 && NB % B == 0 && bpblk == 32 && P == NB * SC
              && N == bpblk * SC && GXC / XG2 == 32 && ws_size >= need;

    if (ok) {
        place_kernel<<<NB, PT, 0, stream>>>((const v2f*)fea, xy, keyA, meta, swz);
        int grid2 = B * (GXC / XG2);        // 512
        void* args[] = { (void*)&keyA, (void*)&meta, (void*)&d_out,
                         (void*)&partials, (void*)&mn, (void*)&bpblk, (void*)&B };
        hipError_t ce = hipLaunchCooperativeKernel((const void*)fused_kernel,
                                                   dim3(grid2), dim3(512),
                                                   args, 0, stream);
        if (ce != hipSuccess) {
            // capture- or occupancy-rejected: R11-proven 3-kernel chain
            rowreduce_kernel<<<NBIN / XG, 512, 0, stream>>>(keyA, meta,
                                                            (float*)d_out,
                                                            partials, bpblk);
            reduce_kernel<<<B * 6, 256, 0, stream>>>(partials, mn, mx, GXC / XG);
            norm_kernel<<<(out_size / 4 + 255) / 256, 256, 0, stream>>>(
                (v4f*)d_out, mn, mx, out_size / 4);
        }
    } else {
        float* mn_f = (float*)ws;
        float* mx_f = (float*)(ws + 256);
        float* part_f = (float*)(ws + 512);
        size_t hdr = 512 + (size_t)B * BPB * 6 * 4;
        unsigned long long* keys = (unsigned long long*)(ws + hdr);
        unsigned char* cntB = (unsigned char*)(ws + hdr + (size_t)S * 8);
        (void)hipMemsetAsync(keys, 0x00, (size_t)S * 9, stream);
        scatter_fb<<<(P + 255) / 256, 256, 0, stream>>>(fea, xy, keys,
                                                        (unsigned*)cntB, N, P);
        fill_fb<<<S / 256, 256, 0, stream>>>(keys, cntB, (float*)d_out, part_f);
        reduce_kernel<<<B * 6, 256, 0, stream>>>(part_f, mn_f, mx_f, BPB);
        norm_kernel<<<(out_size / 4 + 255) / 256, 256, 0, stream>>>(
            (v4f*)d_out, mn_f, mx_f, out_size / 4);
    }
}

// Round 13
// 167.941 us; speedup vs baseline: 1.5193x; 1.5193x over previous
//
#include <hip/hip_runtime.h>
#include <stdint.h>

#define GXC 512
#define GYC 512
#define GXY (GXC * GYC)     // 262144 voxels per batch
#define NB  512             // place blocks
#define SC  8192            // points per block = one flush
#define PT  1024            // place threads per block
#define SPT (SC / PT)       // staged points per thread = 8
#define LBINS 512           // local bins = GXC
#define XG  4               // bins per rowreduce block
#define BPB (GXY / 256)     // fallback fill blocks per batch

typedef float v4f __attribute__((ext_vector_type(4)));
typedef float v2f __attribute__((ext_vector_type(2)));
typedef int   v2i __attribute__((ext_vector_type(2)));

// ---- monotone float <-> sortable-uint mapping ----
__device__ __forceinline__ unsigned f2s(float f) {
    unsigned u = __float_as_uint(f);
    return (u & 0x80000000u) ? ~u : (u | 0x80000000u);
}
__device__ __forceinline__ float s2f(unsigned u) {
    return (u & 0x80000000u) ? __uint_as_float(u ^ 0x80000000u)
                             : __uint_as_float(~u);
}
// key = [ f2s(z) : 32 | f2s(r) top 23 bits | y : 9 ] (R9/R11-verified,
// absmax 0.0039 within tolerance).
__device__ __forceinline__ unsigned long long packkey_y(float z, float r,
                                                        unsigned y) {
    return ((unsigned long long)f2s(z) << 32)
         | (unsigned long long)((f2s(r) & ~511u) | y);
}
__device__ __forceinline__ unsigned long long packkey(float z, float r) {
    return ((unsigned long long)f2s(z) << 32) | (unsigned long long)f2s(r);
}

// XCD swizzle (locality heuristic ONLY).
__device__ __forceinline__ int swizzle(int g, int swz) {
    return swz ? ((g & 7) * (NB / 8) + (g >> 3)) : g;
}

// ================= K1: placement into private per-block segments =========
// (R12's only kept change: zr is an 8B (z,r) ext-vector load, not the full
//  16B float4 -> -32MB input traffic.)
__global__ __launch_bounds__(1024)
void place_kernel(const v2f* __restrict__ zr, const v2i* __restrict__ xy,
                  unsigned long long* __restrict__ keyA,
                  unsigned* __restrict__ meta, int swz) {
    __shared__ unsigned long long skey[SC];       // 64 KB
    __shared__ unsigned lcnt[LBINS], loff[LBINS]; // 4 KB
    __shared__ unsigned wsum[8];
    int t = threadIdx.x;
    int blk = swizzle(blockIdx.x, swz);
    int start = blk * SC;
    if (t < LBINS) lcnt[t] = 0;
    __syncthreads();

    unsigned long long k[SPT]; unsigned lb[SPT], rk[SPT];
    #pragma unroll
    for (int kk = 0; kk < SPT; ++kk) {
        int p = start + t + kk * PT;
        v2i q = __builtin_nontemporal_load(xy + p);
        v2f f = __builtin_nontemporal_load(zr + 2 * p + 1);  // (z, r) at +8B
        k[kk]  = packkey_y(f.x, f.y, (unsigned)q.y);
        lb[kk] = (unsigned)q.x;
        rk[kk] = atomicAdd(&lcnt[q.x], 1u);
    }
    __syncthreads();

    // exclusive scan of lcnt[512] using first 512 threads
    unsigned c = 0, inc = 0;
    if (t < LBINS) {
        c = lcnt[t];
        inc = c;
        int lane = t & 63;
        #pragma unroll
        for (int off = 1; off < 64; off <<= 1) {
            unsigned o = __shfl_up(inc, off);
            if (lane >= off) inc += o;
        }
        if (lane == 63) wsum[t >> 6] = inc;
    }
    __syncthreads();
    if (t < 8) {
        unsigned v = wsum[t], i2 = v;
        #pragma unroll
        for (int off = 1; off < 8; off <<= 1) {
            unsigned o = __shfl_up(i2, off, 8);
            if (t >= off) i2 += o;
        }
        wsum[t] = i2 - v;
    }
    __syncthreads();
    if (t < LBINS) loff[t] = inc - c + wsum[t >> 6];
    __syncthreads();

    // stage bin-grouped
    #pragma unroll
    for (int kk = 0; kk < SPT; ++kk)
        skey[loff[lb[kk]] + rk[kk]] = k[kk];
    __syncthreads();

    // flush: sequential coalesced stores + packed metadata
    unsigned long long* dst = keyA + (size_t)blk * SC;
    #pragma unroll
    for (int kk = 0; kk < SPT; ++kk) {
        int s = t + kk * PT;
        dst[s] = skey[s];
    }
    if (t < LBINS)
        meta[(size_t)blk * LBINS + t] = (loff[t] << 16) | lcnt[t];
}

// ================= K2: rowreduce (R11-proven, XG=4) =======================
__global__ __launch_bounds__(512)
void rowreduce_kernel(const unsigned long long* __restrict__ keyA,
                      const unsigned* __restrict__ meta,
                      float* __restrict__ out,
                      float* __restrict__ partials,
                      int bpblk) {
    __shared__ unsigned long long sk[XG * 512];   // 16 KB
    __shared__ unsigned scnt[XG * 512];           // 8 KB
    __shared__ float red[8][6];
    int t = threadIdx.x;
    int g = blockIdx.x;
    int batch = g >> 7;                           // 128 x-groups per batch
    int x0 = (g & 127) * XG;
    for (int i = t; i < XG * 512; i += 512) { sk[i] = 0; scnt[i] = 0; }
    __syncthreads();

    int seg = t >> 4, l16 = t & 15;               // 16 lanes per segment
    size_t sidx = (size_t)(batch * bpblk + seg);
    uint4 m = *(const uint4*)(meta + sidx * LBINS + x0);
    unsigned lo0 = m.x >> 16;
    unsigned b1 = m.x & 0xFFFFu;
    unsigned b2 = b1 + (m.y & 0xFFFFu);
    unsigned b3 = b2 + (m.z & 0xFFFFu);
    unsigned tot = b3 + (m.w & 0xFFFFu);
    const unsigned long long* src = keyA + sidx * SC + lo0;
    for (unsigned r = l16; r < tot; r += 16) {
        unsigned long long k = src[r];            // contiguous slice
        int bin = (r >= b1) + (r >= b2) + (r >= b3);
        unsigned y = (unsigned)k & 511u;
        atomicMax(&sk[(bin << 9) + y], k);
        atomicAdd(&scnt[(bin << 9) + y], 1u);
    }
    __syncthreads();

    size_t ob = ((size_t)batch * 3) << 18;
    size_t xoff = (size_t)x0 << 9;
    float n0 = INFINITY, mx0 = -INFINITY, n1 = INFINITY, mx1 = -INFINITY,
          n2 = INFINITY, mx2 = -INFINITY;
    for (int i = t; i < XG * 512; i += 512) {
        unsigned cv = scnt[i];
        float h0 = 0.0f, r = 0.0f;
        if (cv) {
            unsigned long long k = sk[i];
            h0 = s2f((unsigned)(k >> 32));
            r  = s2f((unsigned)k & ~511u);
        }
        float cf = (float)cv;
        out[ob + xoff + i] = h0;
        out[ob + (size_t)GXY + xoff + i] = r;
        out[ob + (size_t)(2 * GXY) + xoff + i] = cf;
        n0 = fminf(n0, h0); mx0 = fmaxf(mx0, h0);
        n1 = fminf(n1, r);  mx1 = fmaxf(mx1, r);
        n2 = fminf(n2, cf); mx2 = fmaxf(mx2, cf);
    }
    #pragma unroll
    for (int off = 32; off; off >>= 1) {
        n0 = fminf(n0, __shfl_down(n0, off));  mx0 = fmaxf(mx0, __shfl_down(mx0, off));
        n1 = fminf(n1, __shfl_down(n1, off));  mx1 = fmaxf(mx1, __shfl_down(mx1, off));
        n2 = fminf(n2, __shfl_down(n2, off));  mx2 = fmaxf(mx2, __shfl_down(mx2, off));
    }
    int lane = t & 63, wave = t >> 6;
    if (lane == 0) {
        red[wave][0] = n0; red[wave][1] = mx0;
        red[wave][2] = n1; red[wave][3] = mx1;
        red[wave][4] = n2; red[wave][5] = mx2;
    }
    __syncthreads();
    if (t < 6) {
        float v = red[0][t];
        bool isMin = (t & 1) == 0;
        #pragma unroll
        for (int w = 1; w < 8; ++w)
            v = isMin ? fminf(v, red[w][t]) : fmaxf(v, red[w][t]);
        partials[(size_t)g * 6 + t] = v;          // plain store, no contention
    }
}

// ================= K3: partials -> mn/mx ==================================
__global__ void reduce_kernel(const float* __restrict__ partials,
                              float* __restrict__ mn,
                              float* __restrict__ mx,
                              int rows) {
    int b = blockIdx.x / 6;
    int j = blockIdx.x - b * 6;
    bool isMin = (j & 1) == 0;
    float v = isMin ? INFINITY : -INFINITY;
    for (int i = threadIdx.x; i < rows; i += blockDim.x) {
        float p = partials[((size_t)b * rows + i) * 6 + j];
        v = isMin ? fminf(v, p) : fmaxf(v, p);
    }
    #pragma unroll
    for (int off = 32; off; off >>= 1) {
        float o = __shfl_down(v, off);
        v = isMin ? fminf(v, o) : fmaxf(v, o);
    }
    __shared__ float red[4];
    int lane = threadIdx.x & 63, wave = threadIdx.x >> 6;
    if (lane == 0) red[wave] = v;
    __syncthreads();
    if (threadIdx.x == 0) {
        #pragma unroll
        for (int w = 1; w < 4 && w < (int)(blockDim.x >> 6); ++w)
            v = isMin ? fminf(v, red[w]) : fmaxf(v, red[w]);
        int slot = b * 3 + (j >> 1);
        if (isMin) mn[slot] = v; else mx[slot] = v;
    }
}

// ================= K4: in-place normalize, nontemporal ====================
__global__ void norm_kernel(v4f* __restrict__ out,
                            const float* __restrict__ mn,
                            const float* __restrict__ mx,
                            int total4) {
    int i = blockIdx.x * blockDim.x + threadIdx.x;
    if (i >= total4) return;
    int slot = i >> 16;
    float lo = mn[slot];
    float inv = 1.0f / (mx[slot] - lo);
    v4f v = __builtin_nontemporal_load(out + i);
    v.x = (v.x - lo) * inv;
    v.y = (v.y - lo) * inv;
    v.z = (v.z - lo) * inv;
    v.w = (v.w - lo) * inv;
    __builtin_nontemporal_store(v, out + i);
}

// ================= fallback path (R4 structure) =================
__global__ void scatter_fb(const v4f* __restrict__ fea, const v2i* __restrict__ xy,
                           unsigned long long* __restrict__ keys,
                           unsigned* __restrict__ cnt32, int N, int P) {
    int p = blockIdx.x * blockDim.x + threadIdx.x;
    if (p >= P) return;
    v2i q = __builtin_nontemporal_load(xy + p);
    v4f f = __builtin_nontemporal_load(fea + p);
    int vid = ((p / N) * GXC + q.x) * GYC + q.y;
    atomicMax(&keys[vid], packkey(f.z, f.w));
    atomicAdd(&cnt32[vid >> 2], 1u << ((vid & 3) * 8));
}

__global__ void fill_fb(const unsigned long long* __restrict__ keys,
                        const unsigned char* __restrict__ cntB,
                        float* __restrict__ out, float* __restrict__ partials) {
    int g = blockIdx.x;
    int batch = g / BPB, blkInB = g - batch * BPB;
    int rem = blkInB * 256 + threadIdx.x;
    int s = batch * GXY + rem;
    unsigned c = cntB[s];
    float h0 = 0.0f, r = 0.0f;
    if (c) {
        unsigned long long k = keys[s];
        h0 = s2f((unsigned)(k >> 32));
        r  = s2f((unsigned)(k & 0xFFFFFFFFull));
    }
    float cf = (float)c;
    size_t base = (size_t)batch * 3 * GXY + rem;
    out[base] = h0; out[base + GXY] = r; out[base + 2 * GXY] = cf;
    float n0 = h0, x0 = h0, n1 = r, x1 = r, n2 = cf, x2 = cf;
    #pragma unroll
    for (int off = 32; off; off >>= 1) {
        n0 = fminf(n0, __shfl_down(n0, off)); x0 = fmaxf(x0, __shfl_down(x0, off));
        n1 = fminf(n1, __shfl_down(n1, off)); x1 = fmaxf(x1, __shfl_down(x1, off));
        n2 = fminf(n2, __shfl_down(n2, off)); x2 = fmaxf(x2, __shfl_down(x2, off));
    }
    __shared__ float red[4][6];
    int lane = threadIdx.x & 63, wave = threadIdx.x >> 6;
    if (lane == 0) {
        red[wave][0] = n0; red[wave][1] = x0; red[wave][2] = n1;
        red[wave][3] = x1; red[wave][4] = n2; red[wave][5] = x2;
    }
    __syncthreads();
    if (threadIdx.x < 6) {
        int j = threadIdx.x;
        float v = red[0][j];
        bool isMin = (j & 1) == 0;
        #pragma unroll
        for (int w = 1; w < 4; ++w)
            v = isMin ? fminf(v, red[w][j]) : fmaxf(v, red[w][j]);
        partials[(size_t)(batch * BPB + blkInB) * 6 + j] = v;
    }
}

extern "C" void kernel_launch(void* const* d_in, const int* in_sizes, int n_in,
                              void* d_out, int out_size, void* d_ws, size_t ws_size,
                              hipStream_t stream) {
    const v4f* fea = (const v4f*)d_in[0];   // [B, N, 4] f32
    const v2i* xy  = (const v2i*)d_in[1];   // [B, N, 2] i32

    int P = in_sizes[0] / 4;
    int B = out_size / (3 * GXY);
    int N = (B > 0) ? P / B : 0;
    int S = B * GXY;
    int NBIN = B * GXC;
    int bpblk = (B > 0) ? NB / B : 0;       // place blocks (=segments) per batch

    char* ws = (char*)d_ws;
    unsigned long long* keyA = (unsigned long long*)ws;
    size_t o = (size_t)P * 8;
    unsigned* meta = (unsigned*)(ws + o);   o += (size_t)NB * LBINS * 4;
    float* partials = (float*)(ws + o);     o += (size_t)(NBIN / XG) * 6 * 4;
    float* mn = (float*)(ws + o);           o += (size_t)B * 3 * 4;
    float* mx = (float*)(ws + o);           o += (size_t)B * 3 * 4;
    size_t need = o;

    int swz = (B % 8 == 0) ? 1 : 0;

    // Gate: exact bench shape (B=16, N=262144): one 8192-pt flush per block,
    // 32 segments per batch, 512-bin batches.
    bool ok = B > 0 && NB % B == 0 && bpblk == 32 && P == NB * SC
              && N == bpblk * SC && ws_size >= need;

    if (ok) {
        // every ws byte used is fully overwritten each call -> no memsets
        // despite 0xAA re-poison.
        place_kernel<<<NB, PT, 0, stream>>>((const v2f*)fea, xy, keyA, meta, swz);
        rowreduce_kernel<<<NBIN / XG, 512, 0, stream>>>(keyA, meta,
                                                        (float*)d_out, partials,
                                                        bpblk);
        reduce_kernel<<<B * 6, 256, 0, stream>>>(partials, mn, mx, GXC / XG);
        norm_kernel<<<(out_size / 4 + 255) / 256, 256, 0, stream>>>(
            (v4f*)d_out, mn, mx, out_size / 4);
    } else {
        float* mn_f = (float*)ws;
        float* mx_f = (float*)(ws + 256);
        float* part_f = (float*)(ws + 512);
        size_t hdr = 512 + (size_t)B * BPB * 6 * 4;
        unsigned long long* keys = (unsigned long long*)(ws + hdr);
        unsigned char* cntB = (unsigned char*)(ws + hdr + (size_t)S * 8);
        (void)hipMemsetAsync(keys, 0x00, (size_t)S * 9, stream);
        scatter_fb<<<(P + 255) / 256, 256, 0, stream>>>(fea, xy, keys,
                                                        (unsigned*)cntB, N, P);
        fill_fb<<<S / 256, 256, 0, stream>>>(keys, cntB, (float*)d_out, part_f);
        reduce_kernel<<<B * 6, 256, 0, stream>>>(part_f, mn_f, mx_f, BPB);
        norm_kernel<<<(out_size / 4 + 255) / 256, 256, 0, stream>>>(
            (v4f*)d_out, mn_f, mx_f, out_size / 4);
    }
}